// Round 3
// baseline (212.002 us; speedup 1.0000x reference)
//
#include <hip/hip_runtime.h>
#include <hip/hip_bf16.h>
#include <stdint.h>

#define N_MODELS 16
#define IN_F 1024
#define OUT_F 1024
#define N_TOK 8192
#define MAX_MT 80          // max m-tiles: 64 full + up to 15 fragmentation, padded

typedef unsigned short u16;
using us4   = __attribute__((ext_vector_type(4))) unsigned short;
using s16x8 = __attribute__((ext_vector_type(8))) short;
using f32x4 = __attribute__((ext_vector_type(4))) float;

__device__ __forceinline__ u16 f2bf(float f) {
    union { float f; uint32_t u; } v;
    v.f = f;
    uint32_t u = v.u;
    u += 0x7fffu + ((u >> 16) & 1u);   // RNE
    return (u16)(u >> 16);
}

__device__ __forceinline__ void gload16(const u16* g, u16* l) {
    // async global->LDS DMA, 16 B/lane; LDS dest = wave-uniform base + lane*16
    __builtin_amdgcn_global_load_lds(
        (const __attribute__((address_space(1))) void*)g,
        (__attribute__((address_space(3))) void*)l, 16, 0, 0);
}

// ---------------- bucketing: hist -> scan -> scatter (parallel) ----------------
__global__ void hist_kernel(const int* __restrict__ idxs, int* __restrict__ ghist) {
    __shared__ int cnt[N_MODELS];
    int t = threadIdx.x;
    if (t < N_MODELS) cnt[t] = 0;
    __syncthreads();
    int i = blockIdx.x * 256 + t;
    atomicAdd(&cnt[idxs[i]], 1);
    __syncthreads();
    if (t < N_MODELS) atomicAdd(&ghist[t], cnt[t]);
}

__global__ void scan_kernel(const int* __restrict__ ghist,
                            int* __restrict__ offs, int* __restrict__ tile_off,
                            int* __restrict__ gcur) {
    if (threadIdx.x == 0) {
        int o = 0, to = 0;
        for (int e = 0; e < N_MODELS; ++e) {
            offs[e] = o; tile_off[e] = to; gcur[e] = o;
            to += (ghist[e] + 127) >> 7;
            o  += ghist[e];
        }
        offs[N_MODELS] = o; tile_off[N_MODELS] = to;
    }
}

__global__ void scatter_kernel(const int* __restrict__ idxs,
                               int* __restrict__ gcur, int* __restrict__ perm) {
    int i = blockIdx.x * 256 + threadIdx.x;
    int e = idxs[i];
    int p = atomicAdd(&gcur[e], 1);   // order within expert is irrelevant
    perm[p] = i;
}

// ---------------- w-prep: direct fp32 [e][k][n] -> frag-major bf16, no LDS ----------------
// wT layout (u16): ((((e*8 + nt)*32 + kb)*4 + q)*128 + n)*8 + j
__global__ __launch_bounds__(256)
void wprep_kernel(const float* __restrict__ w, u16* __restrict__ wT) {
    int bx  = blockIdx.x;            // (e, nt, kb2): 16*8*16 = 2048 blocks, kb2 = 64-k group
    int e   = bx >> 7;
    int nt  = (bx >> 4) & 7;
    int kb2 = bx & 15;
    const float* wp = w + (size_t)e * (IN_F * OUT_F) + (size_t)kb2 * 64 * OUT_F + nt * 128;
    u16* ob = wT + ((size_t)(e * 8 + nt) * 32 + kb2 * 2) * 4096;
    int n    = threadIdx.x & 127;
    int half = threadIdx.x >> 7;     // 0..1
#pragma unroll
    for (int i = 0; i < 4; ++i) {
        int ko = half + i * 2;       // k-octet within the 64-k group (0..7)
        s16x8 v;
#pragma unroll
        for (int j = 0; j < 8; ++j)
            v[j] = (short)f2bf(wp[(size_t)(ko * 8 + j) * OUT_F + n]);
        *(s16x8*)(ob + ((size_t)((ko >> 2) * 4 + (ko & 3)) * 128 + n) * 8) = v;
    }
}

// ---------------- x-prep: gathered fp32 rows -> frag-major bf16 ----------------
// xg layout (u16): mt*131072 + kb*4096 + q*1024 + r*8 + j
__global__ __launch_bounds__(256)
void xprep_kernel(const float* __restrict__ x,
                  const int* __restrict__ perm, const int* __restrict__ offs,
                  const int* __restrict__ tile_off, u16* __restrict__ xg) {
    __shared__ u16 sh[4096];
    int t   = threadIdx.x;
    int bx2 = blockIdx.x;            // (mt, kg): mt*8 + kg, kg = 128-k group
    int mt  = bx2 >> 3;
    int kg  = bx2 & 7;
    int total = tile_off[N_MODELS];
    if (mt >= total) return;
    int e = 0;
    while (tile_off[e + 1] <= mt) ++e;
    int s0   = offs[e] + (mt - tile_off[e]) * 128;
    int sEnd = offs[e + 1];
    int r0   = t >> 3;               // +i*32
    int apos = t & 7;
    int toks[4];
#pragma unroll
    for (int i = 0; i < 4; ++i) {
        int r = r0 + i * 32;
        toks[i] = (s0 + r < sEnd) ? perm[s0 + r] : -1;
    }
    u16* outx = xg + (size_t)mt * 32 * 4096;
    for (int kb4 = 0; kb4 < 4; ++kb4) {
        int kb = kg * 4 + kb4;
#pragma unroll
        for (int i = 0; i < 4; ++i) {
            int r = r0 + i * 32;
            int k = kb * 32 + apos * 4;
            float4 v;
            if (toks[i] >= 0) v = *(const float4*)(x + (size_t)toks[i] * IN_F + k);
            else              v = make_float4(0.f, 0.f, 0.f, 0.f);
            us4 pk; pk.x = f2bf(v.x); pk.y = f2bf(v.y); pk.z = f2bf(v.z); pk.w = f2bf(v.w);
            *(us4*)(&sh[(apos >> 1) * 1024 + r * 8 + (apos & 1) * 4]) = pk;
        }
        __syncthreads();
#pragma unroll
        for (int i = 0; i < 2; ++i) {
            int c = t + i * 256;     // 16B chunk id, 512 total
            *(s16x8*)(outx + (size_t)kb * 4096 + c * 8) = *(const s16x8*)(&sh[c * 8]);
        }
        __syncthreads();
    }
}

// ---------------- grouped GEMM + bias + relu (m97 structure) ----------------
__global__ __launch_bounds__(256)
void gemm_kernel(const u16* __restrict__ xg, const u16* __restrict__ wT,
                 const float* __restrict__ bias,
                 const int* __restrict__ perm, const int* __restrict__ offs,
                 const int* __restrict__ tile_off,
                 float* __restrict__ out)
{
    __shared__ u16 As[4096];
    __shared__ u16 Bs[4096];
    __shared__ int   permS[128];
    __shared__ float biasS[128];
    __shared__ int   toS[N_MODELS + 1];

    int t  = threadIdx.x;
    int bt = blockIdx.y;            // flat m-tile id
    int nt = blockIdx.x;            // n-tile id

    if (t <= N_MODELS) toS[t] = tile_off[t];
    __syncthreads();
    if (bt >= toS[N_MODELS]) return;   // uniform

    int e = 0;
    while (toS[e + 1] <= bt) ++e;
    int s0   = offs[e] + (bt - toS[e]) * 128;
    int sEnd = offs[e + 1];
    int mValid = sEnd - s0; if (mValid > 128) mValid = 128;

    if (t < 128) {
        permS[t] = (s0 + t < sEnd) ? perm[s0 + t] : 0;
        biasS[t] = bias[(size_t)e * OUT_F + nt * 128 + t];
    }

    const u16* atile = xg + (size_t)bt * 32 * 4096;
    const u16* btile = wT + ((size_t)(e * 8 + nt) * 32) * 4096;

    int lane = t & 63;
    int wv   = t >> 6;
    int wm   = (wv >> 1) * 64;
    int wn   = (wv & 1) * 64;
    int m    = lane & 15;
    int q    = lane >> 4;

    f32x4 acc[4][4];
#pragma unroll
    for (int i = 0; i < 4; ++i)
#pragma unroll
        for (int j = 0; j < 4; ++j)
            acc[i][j] = (f32x4){0.f, 0.f, 0.f, 0.f};

    int c = wv * 2;   // this wave's 1 KB chunk base (8 chunks per 8 KB tile)

    for (int kb = 0; kb < 32; ++kb) {
        const u16* ga = atile + kb * 4096;
        const u16* gb = btile + kb * 4096;
        gload16(ga + (c    ) * 512 + lane * 8, &As[(c    ) * 512]);
        gload16(ga + (c + 1) * 512 + lane * 8, &As[(c + 1) * 512]);
        gload16(gb + (c    ) * 512 + lane * 8, &Bs[(c    ) * 512]);
        gload16(gb + (c + 1) * 512 + lane * 8, &Bs[(c + 1) * 512]);
        __syncthreads();

        s16x8 af[4], bf[4];
#pragma unroll
        for (int mt2 = 0; mt2 < 4; ++mt2)
            af[mt2] = *(const s16x8*)(&As[q * 1024 + (wm + mt2 * 16 + m) * 8]);
#pragma unroll
        for (int nt2 = 0; nt2 < 4; ++nt2)
            bf[nt2] = *(const s16x8*)(&Bs[q * 1024 + (wn + nt2 * 16 + m) * 8]);
#pragma unroll
        for (int mt2 = 0; mt2 < 4; ++mt2)
#pragma unroll
            for (int nt2 = 0; nt2 < 4; ++nt2)
                acc[mt2][nt2] = __builtin_amdgcn_mfma_f32_16x16x32_bf16(
                    af[mt2], bf[nt2], acc[mt2][nt2], 0, 0, 0);
        __syncthreads();
    }

    // epilogue: bias + relu, scatter rows by perm
#pragma unroll
    for (int mt2 = 0; mt2 < 4; ++mt2) {
        int rbase = wm + mt2 * 16 + q * 4;
#pragma unroll
        for (int i = 0; i < 4; ++i) {
            int r = rbase + i;
            if (r < mValid) {
                int tok = permS[r];
                float* orow = out + (size_t)tok * OUT_F + nt * 128;
#pragma unroll
                for (int nt2 = 0; nt2 < 4; ++nt2) {
                    int col = wn + nt2 * 16 + m;
                    float v = acc[mt2][nt2][i] + biasS[col];
                    orow[col] = v > 0.f ? v : 0.f;
                }
            }
        }
    }
}

extern "C" void kernel_launch(void* const* d_in, const int* in_sizes, int n_in,
                              void* d_out, int out_size, void* d_ws, size_t ws_size,
                              hipStream_t stream) {
    const float* x    = (const float*)d_in[0];
    const int*   idxs = (const int*)d_in[1];
    const float* w    = (const float*)d_in[2];
    const float* b    = (const float*)d_in[3];
    float* out = (float*)d_out;

    // ws layout: wT u16[16M] (32 MB) | xg u16[80*32*4096] (20 MB) | perm | offs | tile_off | ghist | gcur
    u16* wT = (u16*)d_ws;
    u16* xg = wT + (size_t)N_MODELS * IN_F * OUT_F;
    int* perm     = (int*)(xg + (size_t)MAX_MT * 32 * 4096);
    int* offs     = perm + N_TOK;
    int* tile_off = offs + (N_MODELS + 1);
    int* ghist    = tile_off + (N_MODELS + 1);
    int* gcur     = ghist + N_MODELS;

    hipMemsetAsync(ghist, 0, N_MODELS * sizeof(int), stream);
    hist_kernel<<<N_TOK / 256, 256, 0, stream>>>(idxs, ghist);
    scan_kernel<<<1, 64, 0, stream>>>(ghist, offs, tile_off, gcur);
    scatter_kernel<<<N_TOK / 256, 256, 0, stream>>>(idxs, gcur, perm);
    wprep_kernel<<<16 * 8 * 16, 256, 0, stream>>>(w, wT);
    xprep_kernel<<<MAX_MT * 8, 256, 0, stream>>>(x, perm, offs, tile_off, xg);
    gemm_kernel<<<dim3(8, MAX_MT), 256, 0, stream>>>(xg, wT, b, perm, offs, tile_off, out);
}

// Round 4
// 186.255 us; speedup vs baseline: 1.1382x; 1.1382x over previous
//
#include <hip/hip_runtime.h>
#include <hip/hip_bf16.h>
#include <stdint.h>

#define N_MODELS 16
#define IN_F 1024
#define OUT_F 1024
#define N_TOK 8192
#define MAX_MT 80          // max m-tiles: 64 full + up to 15 fragmentation, padded

typedef unsigned short u16;
using us4   = __attribute__((ext_vector_type(4))) unsigned short;
using s16x8 = __attribute__((ext_vector_type(8))) short;
using f32x4 = __attribute__((ext_vector_type(4))) float;

__device__ __forceinline__ u16 f2bf(float f) {
    union { float f; uint32_t u; } v;
    v.f = f;
    uint32_t u = v.u;
    u += 0x7fffu + ((u >> 16) & 1u);   // RNE
    return (u16)(u >> 16);
}

__device__ __forceinline__ void gload16(const u16* g, u16* l) {
    // async global->LDS DMA, 16 B/lane; LDS dest = wave-uniform base + lane*16
    __builtin_amdgcn_global_load_lds(
        (const __attribute__((address_space(1))) void*)g,
        (__attribute__((address_space(3))) void*)l, 16, 0, 0);
}

// ---------------- kernel 1: setup — hist + scan + deterministic rank scatter ----------------
// One block, 256 threads, no atomics, no memset dependency.
#define ROW 17   // LDS row stride (ints) for [256][16] tables -> conflict-free
__global__ __launch_bounds__(256)
void setup_kernel(const int* __restrict__ idxs,
                  int* __restrict__ perm,
                  int* __restrict__ offs,       // [17]
                  int* __restrict__ tile_off)   // [17]
{
    __shared__ int cnt[256 * ROW];
    __shared__ int offsS[N_MODELS + 1];
    int t = threadIdx.x;

#pragma unroll
    for (int e = 0; e < N_MODELS; ++e) cnt[t * ROW + e] = 0;
    __syncthreads();

    // local counts: thread t owns tokens [t*32, t*32+32)
    int base = t * 32;
#pragma unroll
    for (int i = 0; i < 32; ++i) {
        int e = idxs[base + i];
        cnt[t * ROW + e] += 1;
    }
    __syncthreads();

    // inclusive Hillis-Steele prefix over the 256 thread-rows, per expert
#pragma unroll
    for (int s = 1; s < 256; s <<= 1) {
        int v[N_MODELS];
#pragma unroll
        for (int e = 0; e < N_MODELS; ++e)
            v[e] = (t >= s) ? cnt[(t - s) * ROW + e] : 0;
        __syncthreads();
#pragma unroll
        for (int e = 0; e < N_MODELS; ++e)
            cnt[t * ROW + e] += v[e];
        __syncthreads();
    }

    // expert bases + tile offsets (totals live in row 255)
    if (t == 0) {
        int o = 0, to = 0;
        for (int e = 0; e < N_MODELS; ++e) {
            int c = cnt[255 * ROW + e];
            offsS[e] = o;
            offs[e] = o; tile_off[e] = to;
            to += (c + 127) >> 7;
            o  += c;
        }
        offsS[N_MODELS] = o;
        offs[N_MODELS] = o; tile_off[N_MODELS] = to;
    }
    __syncthreads();

    // exclusive start cursor for this thread, per expert
    int cur[N_MODELS];
#pragma unroll
    for (int e = 0; e < N_MODELS; ++e)
        cur[e] = offsS[e] + ((t > 0) ? cnt[(t - 1) * ROW + e] : 0);
    __syncthreads();
#pragma unroll
    for (int e = 0; e < N_MODELS; ++e) cnt[t * ROW + e] = cur[e];

    // rank-write: deterministic perm (stable within each thread's slice)
#pragma unroll
    for (int i = 0; i < 32; ++i) {
        int tok = base + i;
        int e = idxs[tok];
        int p = cnt[t * ROW + e]++;
        perm[p] = tok;
    }
}

// ---------------- kernel 2: prep — fused w-transpose + x-gather to frag-major bf16 ----------------
// wT layout (u16): ((((e*8 + nt)*32 + kb)*4 + q)*128 + n)*8 + j
// xg layout (u16): mt*131072 + kb*4096 + q*1024 + r*8 + j
#define WBLOCKS (16 * 8 * 16)   // 2048 (e, nt, 64-k group)
#define XBLOCKS (MAX_MT * 8)    // 640  (mt, 128-k group)

__global__ __launch_bounds__(256)
void prep_kernel(const float* __restrict__ w, const float* __restrict__ x,
                 const int* __restrict__ perm, const int* __restrict__ offs,
                 const int* __restrict__ tile_off,
                 u16* __restrict__ wT, u16* __restrict__ xg)
{
    int t  = threadIdx.x;
    int bx = blockIdx.x;

    if (bx < WBLOCKS) {
        // ---- w fp32 [k][n] -> wT bf16 frag-major (no LDS, coalesced column reads) ----
        int e   = bx >> 7;
        int nt  = (bx >> 4) & 7;
        int kb2 = bx & 15;           // 64-k group
        const float* wp = w + (size_t)e * (IN_F * OUT_F) + (size_t)kb2 * 64 * OUT_F + nt * 128;
        u16* ob = wT + ((size_t)(e * 8 + nt) * 32 + kb2 * 2) * 4096;
        int n    = t & 127;
        int half = t >> 7;           // 0..1
#pragma unroll
        for (int i = 0; i < 4; ++i) {
            int ko = half + i * 2;   // k-octet within 64-k group (0..7)
            s16x8 v;
#pragma unroll
            for (int j = 0; j < 8; ++j)
                v[j] = (short)f2bf(wp[(size_t)(ko * 8 + j) * OUT_F + n]);
            *(s16x8*)(ob + ((size_t)((ko >> 2) * 4 + (ko & 3)) * 128 + n) * 8) = v;
        }
    } else {
        // ---- x fp32 gathered by perm -> xg bf16 frag-major ----
        __shared__ u16 sh[4096];
        int bx2 = bx - WBLOCKS;
        int mt  = bx2 >> 3;
        int kg  = bx2 & 7;           // 128-k group
        int total = tile_off[N_MODELS];
        if (mt >= total) return;
        int e = 0;
        while (tile_off[e + 1] <= mt) ++e;
        int s0   = offs[e] + (mt - tile_off[e]) * 128;
        int sEnd = offs[e + 1];
        int r0   = t >> 3;
        int apos = t & 7;
        int toks[4];
#pragma unroll
        for (int i = 0; i < 4; ++i) {
            int r = r0 + i * 32;
            toks[i] = (s0 + r < sEnd) ? perm[s0 + r] : -1;
        }
        u16* outx = xg + (size_t)mt * 32 * 4096;
        for (int kb4 = 0; kb4 < 4; ++kb4) {
            int kb = kg * 4 + kb4;
#pragma unroll
            for (int i = 0; i < 4; ++i) {
                int r = r0 + i * 32;
                int k = kb * 32 + apos * 4;
                float4 v;
                if (toks[i] >= 0) v = *(const float4*)(x + (size_t)toks[i] * IN_F + k);
                else              v = make_float4(0.f, 0.f, 0.f, 0.f);
                us4 pk; pk.x = f2bf(v.x); pk.y = f2bf(v.y); pk.z = f2bf(v.z); pk.w = f2bf(v.w);
                *(us4*)(&sh[(apos >> 1) * 1024 + r * 8 + (apos & 1) * 4]) = pk;
            }
            __syncthreads();
#pragma unroll
            for (int i = 0; i < 2; ++i) {
                int c = t + i * 256;
                *(s16x8*)(outx + (size_t)kb * 4096 + c * 8) = *(const s16x8*)(&sh[c * 8]);
            }
            __syncthreads();
        }
    }
}

// ---------------- kernel 3: grouped GEMM + bias + relu (m97 structure) ----------------
__global__ __launch_bounds__(256)
void gemm_kernel(const u16* __restrict__ xg, const u16* __restrict__ wT,
                 const float* __restrict__ bias,
                 const int* __restrict__ perm, const int* __restrict__ offs,
                 const int* __restrict__ tile_off,
                 float* __restrict__ out)
{
    __shared__ u16 As[4096];
    __shared__ u16 Bs[4096];
    __shared__ int   permS[128];
    __shared__ float biasS[128];
    __shared__ int   toS[N_MODELS + 1];

    int t  = threadIdx.x;
    int bt = blockIdx.y;            // flat m-tile id
    int nt = blockIdx.x;            // n-tile id

    if (t <= N_MODELS) toS[t] = tile_off[t];
    __syncthreads();
    if (bt >= toS[N_MODELS]) return;   // uniform

    int e = 0;
    while (toS[e + 1] <= bt) ++e;
    int s0   = offs[e] + (bt - toS[e]) * 128;
    int sEnd = offs[e + 1];
    int mValid = sEnd - s0; if (mValid > 128) mValid = 128;

    if (t < 128) {
        permS[t] = (s0 + t < sEnd) ? perm[s0 + t] : 0;
        biasS[t] = bias[(size_t)e * OUT_F + nt * 128 + t];
    }

    const u16* atile = xg + (size_t)bt * 32 * 4096;
    const u16* btile = wT + ((size_t)(e * 8 + nt) * 32) * 4096;

    int lane = t & 63;
    int wv   = t >> 6;
    int wm   = (wv >> 1) * 64;
    int wn   = (wv & 1) * 64;
    int m    = lane & 15;
    int q    = lane >> 4;

    f32x4 acc[4][4];
#pragma unroll
    for (int i = 0; i < 4; ++i)
#pragma unroll
        for (int j = 0; j < 4; ++j)
            acc[i][j] = (f32x4){0.f, 0.f, 0.f, 0.f};

    int c = wv * 2;   // this wave's 1 KB chunk base (8 chunks per 8 KB tile)

    for (int kb = 0; kb < 32; ++kb) {
        const u16* ga = atile + kb * 4096;
        const u16* gb = btile + kb * 4096;
        gload16(ga + (c    ) * 512 + lane * 8, &As[(c    ) * 512]);
        gload16(ga + (c + 1) * 512 + lane * 8, &As[(c + 1) * 512]);
        gload16(gb + (c    ) * 512 + lane * 8, &Bs[(c    ) * 512]);
        gload16(gb + (c + 1) * 512 + lane * 8, &Bs[(c + 1) * 512]);
        __syncthreads();

        s16x8 af[4], bf[4];
#pragma unroll
        for (int mt2 = 0; mt2 < 4; ++mt2)
            af[mt2] = *(const s16x8*)(&As[q * 1024 + (wm + mt2 * 16 + m) * 8]);
#pragma unroll
        for (int nt2 = 0; nt2 < 4; ++nt2)
            bf[nt2] = *(const s16x8*)(&Bs[q * 1024 + (wn + nt2 * 16 + m) * 8]);
#pragma unroll
        for (int mt2 = 0; mt2 < 4; ++mt2)
#pragma unroll
            for (int nt2 = 0; nt2 < 4; ++nt2)
                acc[mt2][nt2] = __builtin_amdgcn_mfma_f32_16x16x32_bf16(
                    af[mt2], bf[nt2], acc[mt2][nt2], 0, 0, 0);
        __syncthreads();
    }

    // epilogue: bias + relu, scatter rows by perm
#pragma unroll
    for (int mt2 = 0; mt2 < 4; ++mt2) {
        int rbase = wm + mt2 * 16 + q * 4;
#pragma unroll
        for (int i = 0; i < 4; ++i) {
            int r = rbase + i;
            if (r < mValid) {
                int tok = permS[r];
                float* orow = out + (size_t)tok * OUT_F + nt * 128;
#pragma unroll
                for (int nt2 = 0; nt2 < 4; ++nt2) {
                    int col = wn + nt2 * 16 + m;
                    float v = acc[mt2][nt2][i] + biasS[col];
                    orow[col] = v > 0.f ? v : 0.f;
                }
            }
        }
    }
}

extern "C" void kernel_launch(void* const* d_in, const int* in_sizes, int n_in,
                              void* d_out, int out_size, void* d_ws, size_t ws_size,
                              hipStream_t stream) {
    const float* x    = (const float*)d_in[0];
    const int*   idxs = (const int*)d_in[1];
    const float* w    = (const float*)d_in[2];
    const float* b    = (const float*)d_in[3];
    float* out = (float*)d_out;

    // ws layout: wT u16[16M] (32 MB) | xg u16[80*32*4096] (20 MB) | perm | offs | tile_off
    u16* wT = (u16*)d_ws;
    u16* xg = wT + (size_t)N_MODELS * IN_F * OUT_F;
    int* perm     = (int*)(xg + (size_t)MAX_MT * 32 * 4096);
    int* offs     = perm + N_TOK;
    int* tile_off = offs + (N_MODELS + 1);

    setup_kernel<<<1, 256, 0, stream>>>(idxs, perm, offs, tile_off);
    prep_kernel<<<WBLOCKS + XBLOCKS, 256, 0, stream>>>(w, x, perm, offs, tile_off, wT, xg);
    gemm_kernel<<<dim3(8, MAX_MT), 256, 0, stream>>>(xg, wT, b, perm, offs, tile_off, out);
}